// Round 8
// baseline (718.405 us; speedup 1.0000x reference)
//
#include <hip/hip_runtime.h>
#include <hip/hip_cooperative_groups.h>

namespace cg = cooperative_groups;

#define IN_CH   32
#define OUT_CH  64
#define NFILT   16
#define NINACT  (OUT_CH - NFILT)
#define BATCH   32
#define HW      50176     // 224*224
#define HW4     12544     // HW/4 (float4 elements per plane)
#define CHUNKS  49        // HW4 / 256
#define NPLANE  (BATCH * IN_CH)     // 1024
#define NUNITS  (BATCH * CHUNKS)    // 1568
#define NTASK   (BATCH * HW4)       // 401408 conv pixel-tasks
#define FGRID   1280                // 5 blocks/CU co-resident (VGPR 88<=102, LDS 115KB<=160KB)
#define FBLOCK  256

typedef float vfloat4 __attribute__((ext_vector_type(4)));

// ===========================================================================
// Fused cooperative kernel, v3: traffic-minimal (proven R7: FETCH == x once)
// AND occupancy-restored (20 waves/CU vs R7's 8).
//  Phase 1: pool — blocks 0..1023 own one plane each. Blocks are assigned
//           round-robin over the 256 CUs, so every CU has exactly 4
//           pool-active + 1 idle block -> uniform utilization.
//  ---- grid.sync() ----
//  Phase 2: router for all 32 samples, block-wide, redundant per block.
//  Phase 3: conv — contiguous floor-partition of 401,408 flat pixel-tasks:
//           block i owns [i*NTASK/FGRID, (i+1)*NTASK/FGRID) — balanced to
//           +-1 task, no cross-block straggler rounds. nt-stores keep the
//           411 MB output stream out of L3 so x stays Infinity-Cache
//           resident for the conv re-read (measured R7).
// ===========================================================================
__global__ __launch_bounds__(FBLOCK, 5) void fused_kernel(
        const float* __restrict__ x,
        const float* __restrict__ weight,
        const float* __restrict__ bias,
        const float* __restrict__ rw,
        const float* __restrict__ rb,
        float* __restrict__ pooled,
        float* __restrict__ out) {

    const int tid = threadIdx.x;
    const float4* x4 = reinterpret_cast<const float4*>(x);

    // ---------------- Phase 1: pool (1 plane per block, blocks < 1024) ----------------
    __shared__ float red[4];
    if (blockIdx.x < NPLANE) {
        const int p = blockIdx.x;
        const float4* xp = x4 + (size_t)p * HW4;
        float s = 0.f;
        for (int i = tid; i < HW4; i += FBLOCK) {
            float4 v = xp[i];
            s += (v.x + v.y) + (v.z + v.w);
        }
        for (int off = 32; off > 0; off >>= 1)
            s += __shfl_down(s, off, 64);
        if ((tid & 63) == 0) red[tid >> 6] = s;
        __syncthreads();
        if (tid == 0)
            pooled[p] = ((red[0] + red[1]) + (red[2] + red[3])) * (1.0f / (float)HW);
    }

    cg::this_grid().sync();

    // ---------------- Phase 2: router (all samples, block-wide) ----------------
    __shared__ float w_s[OUT_CH][IN_CH];           // 8 KB
    __shared__ float b_s[OUT_CH];
    __shared__ float lg[BATCH][OUT_CH];            // 8 KB
    __shared__ unsigned char act[BATCH][OUT_CH];   // 2 KB
    __shared__ short alist[BATCH][NFILT];          // 1 KB
    __shared__ short ilist[BATCH][NINACT];         // 3 KB

    for (int i = tid; i < OUT_CH * IN_CH; i += FBLOCK)
        (&w_s[0][0])[i] = weight[i];
    if (tid < OUT_CH) b_s[tid] = bias[tid];

    for (int p = tid; p < BATCH * OUT_CH; p += FBLOCK) {
        const int b = p >> 6, o = p & 63;
        float acc = rb[o];
        #pragma unroll
        for (int c = 0; c < IN_CH; ++c)
            acc += pooled[b * IN_CH + c] * rw[o * IN_CH + c];
        lg[b][o] = acc;
    }
    __syncthreads();

    for (int p = tid; p < BATCH * OUT_CH; p += FBLOCK) {
        const int b = p >> 6, o = p & 63;
        const float v = lg[b][o];
        int rank = 0;
        #pragma unroll
        for (int j = 0; j < OUT_CH; ++j) {
            const float lj = lg[b][j];
            rank += (lj > v) || (lj == v && j < o);
        }
        const bool a = (rank < NFILT);
        act[b][o] = a;
        if (a) alist[b][rank] = (short)o;
    }
    __syncthreads();

    for (int p = tid; p < BATCH * OUT_CH; p += FBLOCK) {
        const int b = p >> 6, o = p & 63;
        if (!act[b][o]) {
            int irank = 0;
            for (int j = 0; j < o; ++j) irank += !act[b][j];
            ilist[b][irank] = (short)o;
        }
    }
    __syncthreads();

    // ---------------- Phase 3: conv (balanced contiguous flat partition) ----------------
    vfloat4* o4 = reinterpret_cast<vfloat4*>(out);
    const long long s0 = (long long)blockIdx.x * NTASK / FGRID;
    const long long e0 = (long long)(blockIdx.x + 1) * NTASK / FGRID;

    for (long long t = s0 + tid; t < e0; t += FBLOCK) {
        const int ti  = (int)t;
        const int b   = ti / HW4;            // const-div -> magic multiply
        const int pos = ti - b * HW4;

        float4 xv[IN_CH];
        #pragma unroll
        for (int c = 0; c < IN_CH; ++c)
            xv[c] = x4[(size_t)(b * IN_CH + c) * HW4 + pos];

        const vfloat4 z = {0.f, 0.f, 0.f, 0.f};
        #pragma unroll
        for (int k = 0; k < NINACT; ++k) {
            const int o = ilist[b][k];
            __builtin_nontemporal_store(z, &o4[(size_t)(b * OUT_CH + o) * HW4 + pos]);
        }

        #pragma unroll
        for (int k = 0; k < NFILT; ++k) {
            const int o = alist[b][k];
            const float bv = b_s[o];
            vfloat4 r = {bv, bv, bv, bv};
            #pragma unroll
            for (int c = 0; c < IN_CH; ++c) {
                const float w = w_s[o][c];
                r.x += w * xv[c].x;
                r.y += w * xv[c].y;
                r.z += w * xv[c].z;
                r.w += w * xv[c].w;
            }
            __builtin_nontemporal_store(r, &o4[(size_t)(b * OUT_CH + o) * HW4 + pos]);
        }
    }
}

// ===========================================================================
// Fallback path (proven R5 kernels, 124 us) — used if coop launch refused.
// ===========================================================================
__global__ __launch_bounds__(256) void pool_kernel(const float* __restrict__ x,
                                                   float* __restrict__ pooled) {
    const int bc = blockIdx.x;
    const float4* xp = reinterpret_cast<const float4*>(x) + (size_t)bc * HW4;
    float s = 0.f;
    for (int i = threadIdx.x; i < HW4; i += 256) {
        float4 v = xp[i];
        s += (v.x + v.y) + (v.z + v.w);
    }
    for (int off = 32; off > 0; off >>= 1)
        s += __shfl_down(s, off, 64);
    __shared__ float red[4];
    if ((threadIdx.x & 63) == 0) red[threadIdx.x >> 6] = s;
    __syncthreads();
    if (threadIdx.x == 0)
        pooled[bc] = ((red[0] + red[1]) + (red[2] + red[3])) * (1.0f / (float)HW);
}

__global__ __launch_bounds__(256) void conv_kernel(const float* __restrict__ x,
                                                   const float* __restrict__ weight,
                                                   const float* __restrict__ bias,
                                                   const float* __restrict__ rw,
                                                   const float* __restrict__ rb,
                                                   const float* __restrict__ pooled,
                                                   float* __restrict__ out) {
    __shared__ float w_s[OUT_CH][IN_CH];
    __shared__ float b_s[OUT_CH];
    __shared__ float lg[OUT_CH];
    __shared__ unsigned char act[OUT_CH];
    __shared__ short alist[NFILT];
    __shared__ short ilist[NINACT];

    const int b     = blockIdx.x / CHUNKS;
    const int chunk = blockIdx.x % CHUNKS;

    for (int i = threadIdx.x; i < OUT_CH * IN_CH; i += 256)
        (&w_s[0][0])[i] = weight[i];

    if (threadIdx.x < OUT_CH) {
        const int o = threadIdx.x;
        b_s[o] = bias[o];
        float acc = rb[o];
        #pragma unroll
        for (int c = 0; c < IN_CH; ++c)
            acc += pooled[b * IN_CH + c] * rw[o * IN_CH + c];
        lg[o] = acc;
    }
    __syncthreads();

    if (threadIdx.x < OUT_CH) {
        const int o = threadIdx.x;
        const float v = lg[o];
        int rank = 0;
        #pragma unroll
        for (int j = 0; j < OUT_CH; ++j) {
            const float lj = lg[j];
            rank += (lj > v) || (lj == v && j < o);
        }
        const bool a = (rank < NFILT);
        act[o] = a;
        if (a) alist[rank] = (short)o;
    }
    __syncthreads();

    if (threadIdx.x < OUT_CH) {
        const int o = threadIdx.x;
        if (!act[o]) {
            int irank = 0;
            for (int j = 0; j < o; ++j) irank += !act[j];
            ilist[irank] = (short)o;
        }
    }
    __syncthreads();

    const int pos = chunk * 256 + threadIdx.x;
    const float4* x4 = reinterpret_cast<const float4*>(x);
    vfloat4*      o4 = reinterpret_cast<vfloat4*>(out);

    float4 xv[IN_CH];
    #pragma unroll
    for (int c = 0; c < IN_CH; ++c)
        xv[c] = x4[(size_t)(b * IN_CH + c) * HW4 + pos];

    const vfloat4 z = {0.f, 0.f, 0.f, 0.f};
    #pragma unroll
    for (int k = 0; k < NINACT; ++k) {
        const int o = ilist[k];
        __builtin_nontemporal_store(z, &o4[(size_t)(b * OUT_CH + o) * HW4 + pos]);
    }
    #pragma unroll
    for (int k = 0; k < NFILT; ++k) {
        const int o = alist[k];
        const float bv = b_s[o];
        vfloat4 r = {bv, bv, bv, bv};
        #pragma unroll
        for (int c = 0; c < IN_CH; ++c) {
            const float w = w_s[o][c];
            r.x += w * xv[c].x;
            r.y += w * xv[c].y;
            r.z += w * xv[c].z;
            r.w += w * xv[c].w;
        }
        __builtin_nontemporal_store(r, &o4[(size_t)(b * OUT_CH + o) * HW4 + pos]);
    }
}

// ===========================================================================
extern "C" void kernel_launch(void* const* d_in, const int* in_sizes, int n_in,
                              void* d_out, int out_size, void* d_ws, size_t ws_size,
                              hipStream_t stream) {
    const float* x    = (const float*)d_in[0];
    const float* w    = (const float*)d_in[1];
    const float* bias = (const float*)d_in[2];
    const float* rw   = (const float*)d_in[3];
    const float* rb   = (const float*)d_in[4];
    float* out    = (float*)d_out;
    float* pooled = (float*)d_ws;  // NPLANE floats

    void* args[] = {(void*)&x, (void*)&w, (void*)&bias, (void*)&rw,
                    (void*)&rb, (void*)&pooled, (void*)&out};
    hipError_t err = hipLaunchCooperativeKernel((const void*)fused_kernel,
                                                dim3(FGRID), dim3(FBLOCK),
                                                args, 0, stream);
    if (err != hipSuccess) {
        pool_kernel<<<NPLANE, 256, 0, stream>>>(x, pooled);
        conv_kernel<<<NUNITS, 256, 0, stream>>>(x, w, bias, rw, rb, pooled, out);
    }
}

// Round 9
// 516.081 us; speedup vs baseline: 1.3920x; 1.3920x over previous
//
#include <hip/hip_runtime.h>
#include <hip/hip_cooperative_groups.h>

namespace cg = cooperative_groups;

#define IN_CH   32
#define OUT_CH  64
#define NFILT   16
#define NINACT  (OUT_CH - NFILT)
#define BATCH   32
#define HW      50176     // 224*224
#define HW4     12544     // HW/4 (float4 elements per plane)
#define CHUNKS  49        // HW4 / 256
#define NPLANE  (BATCH * IN_CH)     // 1024
#define NUNITS  (BATCH * CHUNKS)    // 1568
#define NTASK   (BATCH * HW4)       // 401408 conv pixel-tasks
#define FGRID   1024                // 4 blocks/CU; VGPR cap 128 (no spill), LDS 92KB/CU
#define FBLOCK  256
#define TPB     (NTASK / FGRID)     // 392 tasks per block, exact

typedef float vfloat4 __attribute__((ext_vector_type(4)));

// ===========================================================================
// Fused cooperative kernel, v4.
//  R7 proved the traffic floor (FETCH == one x read; nt-stores protect L3).
//  R8 proved min-waves=5 causes VGPR spill (48 VGPR, 1.4 GB scratch).
//  v4: grid=1024 x launch_bounds(256,4): VGPR cap 128 >= natural ~88,
//      16 waves/CU (2x R7), exact load balance in both phases.
//  Phase 1: pool — block i owns plane i (1024 planes / 1024 blocks).
//  ---- grid.sync() ----
//  Phase 2: router for all 32 samples, block-wide, redundant per block.
//  Phase 3: conv — block i owns tasks [392*i, 392*(i+1)), stride-256
//           within block (coalesced). nt-stores keep the 411 MB output
//           stream out of L3 so the conv x-re-read stays L3-resident.
// ===========================================================================
__global__ __launch_bounds__(FBLOCK, 4) void fused_kernel(
        const float* __restrict__ x,
        const float* __restrict__ weight,
        const float* __restrict__ bias,
        const float* __restrict__ rw,
        const float* __restrict__ rb,
        float* __restrict__ pooled,
        float* __restrict__ out) {

    const int tid = threadIdx.x;
    const float4* x4 = reinterpret_cast<const float4*>(x);

    // ---------------- Phase 1: pool (exactly 1 plane per block) ----------------
    __shared__ float red[4];
    {
        const int p = blockIdx.x;                    // 0..1023
        const float4* xp = x4 + (size_t)p * HW4;
        float s = 0.f;
        for (int i = tid; i < HW4; i += FBLOCK) {
            float4 v = xp[i];
            s += (v.x + v.y) + (v.z + v.w);
        }
        for (int off = 32; off > 0; off >>= 1)
            s += __shfl_down(s, off, 64);
        if ((tid & 63) == 0) red[tid >> 6] = s;
        __syncthreads();
        if (tid == 0)
            pooled[p] = ((red[0] + red[1]) + (red[2] + red[3])) * (1.0f / (float)HW);
    }

    cg::this_grid().sync();

    // ---------------- Phase 2: router (all samples, block-wide) ----------------
    __shared__ float w_s[OUT_CH][IN_CH];           // 8 KB
    __shared__ float b_s[OUT_CH];
    __shared__ float lg[BATCH][OUT_CH];            // 8 KB
    __shared__ unsigned char act[BATCH][OUT_CH];   // 2 KB
    __shared__ short alist[BATCH][NFILT];          // 1 KB
    __shared__ short ilist[BATCH][NINACT];         // 3 KB

    for (int i = tid; i < OUT_CH * IN_CH; i += FBLOCK)
        (&w_s[0][0])[i] = weight[i];
    if (tid < OUT_CH) b_s[tid] = bias[tid];

    for (int p = tid; p < BATCH * OUT_CH; p += FBLOCK) {
        const int b = p >> 6, o = p & 63;
        float acc = rb[o];
        #pragma unroll
        for (int c = 0; c < IN_CH; ++c)
            acc += pooled[b * IN_CH + c] * rw[o * IN_CH + c];
        lg[b][o] = acc;
    }
    __syncthreads();

    for (int p = tid; p < BATCH * OUT_CH; p += FBLOCK) {
        const int b = p >> 6, o = p & 63;
        const float v = lg[b][o];
        int rank = 0;
        #pragma unroll
        for (int j = 0; j < OUT_CH; ++j) {
            const float lj = lg[b][j];
            rank += (lj > v) || (lj == v && j < o);
        }
        const bool a = (rank < NFILT);
        act[b][o] = a;
        if (a) alist[b][rank] = (short)o;
    }
    __syncthreads();

    for (int p = tid; p < BATCH * OUT_CH; p += FBLOCK) {
        const int b = p >> 6, o = p & 63;
        if (!act[b][o]) {
            int irank = 0;
            for (int j = 0; j < o; ++j) irank += !act[b][j];
            ilist[b][irank] = (short)o;
        }
    }
    __syncthreads();

    // ---------------- Phase 3: conv (exact contiguous partition, 392/block) ----------------
    vfloat4* o4 = reinterpret_cast<vfloat4*>(out);
    const int s0 = blockIdx.x * TPB;
    const int e0 = s0 + TPB;

    for (int t = s0 + tid; t < e0; t += FBLOCK) {
        const int b   = t / HW4;            // const-div -> magic multiply
        const int pos = t - b * HW4;

        float4 xv[IN_CH];
        #pragma unroll
        for (int c = 0; c < IN_CH; ++c)
            xv[c] = x4[(size_t)(b * IN_CH + c) * HW4 + pos];

        const vfloat4 z = {0.f, 0.f, 0.f, 0.f};
        #pragma unroll
        for (int k = 0; k < NINACT; ++k) {
            const int o = ilist[b][k];
            __builtin_nontemporal_store(z, &o4[(size_t)(b * OUT_CH + o) * HW4 + pos]);
        }

        #pragma unroll
        for (int k = 0; k < NFILT; ++k) {
            const int o = alist[b][k];
            const float bv = b_s[o];
            vfloat4 r = {bv, bv, bv, bv};
            #pragma unroll
            for (int c = 0; c < IN_CH; ++c) {
                const float w = w_s[o][c];
                r.x += w * xv[c].x;
                r.y += w * xv[c].y;
                r.z += w * xv[c].z;
                r.w += w * xv[c].w;
            }
            __builtin_nontemporal_store(r, &o4[(size_t)(b * OUT_CH + o) * HW4 + pos]);
        }
    }
}

// ===========================================================================
// Fallback path (proven R5 kernels, 124 us) — used if coop launch refused.
// ===========================================================================
__global__ __launch_bounds__(256) void pool_kernel(const float* __restrict__ x,
                                                   float* __restrict__ pooled) {
    const int bc = blockIdx.x;
    const float4* xp = reinterpret_cast<const float4*>(x) + (size_t)bc * HW4;
    float s = 0.f;
    for (int i = threadIdx.x; i < HW4; i += 256) {
        float4 v = xp[i];
        s += (v.x + v.y) + (v.z + v.w);
    }
    for (int off = 32; off > 0; off >>= 1)
        s += __shfl_down(s, off, 64);
    __shared__ float red[4];
    if ((threadIdx.x & 63) == 0) red[threadIdx.x >> 6] = s;
    __syncthreads();
    if (threadIdx.x == 0)
        pooled[bc] = ((red[0] + red[1]) + (red[2] + red[3])) * (1.0f / (float)HW);
}

__global__ __launch_bounds__(256) void conv_kernel(const float* __restrict__ x,
                                                   const float* __restrict__ weight,
                                                   const float* __restrict__ bias,
                                                   const float* __restrict__ rw,
                                                   const float* __restrict__ rb,
                                                   const float* __restrict__ pooled,
                                                   float* __restrict__ out) {
    __shared__ float w_s[OUT_CH][IN_CH];
    __shared__ float b_s[OUT_CH];
    __shared__ float lg[OUT_CH];
    __shared__ unsigned char act[OUT_CH];
    __shared__ short alist[NFILT];
    __shared__ short ilist[NINACT];

    const int b     = blockIdx.x / CHUNKS;
    const int chunk = blockIdx.x % CHUNKS;

    for (int i = threadIdx.x; i < OUT_CH * IN_CH; i += 256)
        (&w_s[0][0])[i] = weight[i];

    if (threadIdx.x < OUT_CH) {
        const int o = threadIdx.x;
        b_s[o] = bias[o];
        float acc = rb[o];
        #pragma unroll
        for (int c = 0; c < IN_CH; ++c)
            acc += pooled[b * IN_CH + c] * rw[o * IN_CH + c];
        lg[o] = acc;
    }
    __syncthreads();

    if (threadIdx.x < OUT_CH) {
        const int o = threadIdx.x;
        const float v = lg[o];
        int rank = 0;
        #pragma unroll
        for (int j = 0; j < OUT_CH; ++j) {
            const float lj = lg[j];
            rank += (lj > v) || (lj == v && j < o);
        }
        const bool a = (rank < NFILT);
        act[o] = a;
        if (a) alist[rank] = (short)o;
    }
    __syncthreads();

    if (threadIdx.x < OUT_CH) {
        const int o = threadIdx.x;
        if (!act[o]) {
            int irank = 0;
            for (int j = 0; j < o; ++j) irank += !act[j];
            ilist[irank] = (short)o;
        }
    }
    __syncthreads();

    const int pos = chunk * 256 + threadIdx.x;
    const float4* x4 = reinterpret_cast<const float4*>(x);
    vfloat4*      o4 = reinterpret_cast<vfloat4*>(out);

    float4 xv[IN_CH];
    #pragma unroll
    for (int c = 0; c < IN_CH; ++c)
        xv[c] = x4[(size_t)(b * IN_CH + c) * HW4 + pos];

    const vfloat4 z = {0.f, 0.f, 0.f, 0.f};
    #pragma unroll
    for (int k = 0; k < NINACT; ++k) {
        const int o = ilist[k];
        __builtin_nontemporal_store(z, &o4[(size_t)(b * OUT_CH + o) * HW4 + pos]);
    }
    #pragma unroll
    for (int k = 0; k < NFILT; ++k) {
        const int o = alist[k];
        const float bv = b_s[o];
        vfloat4 r = {bv, bv, bv, bv};
        #pragma unroll
        for (int c = 0; c < IN_CH; ++c) {
            const float w = w_s[o][c];
            r.x += w * xv[c].x;
            r.y += w * xv[c].y;
            r.z += w * xv[c].z;
            r.w += w * xv[c].w;
        }
        __builtin_nontemporal_store(r, &o4[(size_t)(b * OUT_CH + o) * HW4 + pos]);
    }
}

// ===========================================================================
extern "C" void kernel_launch(void* const* d_in, const int* in_sizes, int n_in,
                              void* d_out, int out_size, void* d_ws, size_t ws_size,
                              hipStream_t stream) {
    const float* x    = (const float*)d_in[0];
    const float* w    = (const float*)d_in[1];
    const float* bias = (const float*)d_in[2];
    const float* rw   = (const float*)d_in[3];
    const float* rb   = (const float*)d_in[4];
    float* out    = (float*)d_out;
    float* pooled = (float*)d_ws;  // NPLANE floats

    void* args[] = {(void*)&x, (void*)&w, (void*)&bias, (void*)&rw,
                    (void*)&rb, (void*)&pooled, (void*)&out};
    hipError_t err = hipLaunchCooperativeKernel((const void*)fused_kernel,
                                                dim3(FGRID), dim3(FBLOCK),
                                                args, 0, stream);
    if (err != hipSuccess) {
        pool_kernel<<<NPLANE, 256, 0, stream>>>(x, pooled);
        conv_kernel<<<NUNITS, 256, 0, stream>>>(x, w, bias, rw, rb, pooled, out);
    }
}

// Round 11
// 125.640 us; speedup vs baseline: 5.7180x; 4.1076x over previous
//
#include <hip/hip_runtime.h>

#define IN_CH   32
#define OUT_CH  64
#define NFILT   16
#define NINACT  (OUT_CH - NFILT)
#define BATCH   32
#define HW      50176     // 224*224
#define HW4     12544     // HW/4 (float4 elements per plane)
#define CHUNKS  49        // HW4 / 256

typedef float vfloat4 __attribute__((ext_vector_type(4)));

// ---------------------------------------------------------------------------
// Proven structure (R5: 124.1 us, within ~5% of the 812 MB fabric floor).
//  Kernel 1: pool — one block per (b,c) plane, float4 + shuffle/LDS reduce.
//            Caching loads pull x into the 256 MB Infinity Cache.
//  Kernel 2: router (per-block preamble, jax top_k tie-break) + 1x1 conv.
//            48 inactive channels -> independent zero nt-stores issued while
//            the 32 x-loads are in flight; 16 active channels computed in
//            registers. nt-stores keep the 402 MB output stream from
//            evicting x, so conv's re-read is L3-served (proven R1->R3:
//            161->126 us from nt alone; R7: FETCH == one x read).
// ---------------------------------------------------------------------------
__global__ __launch_bounds__(256) void pool_kernel(const float* __restrict__ x,
                                                   float* __restrict__ pooled) {
    const int bc = blockIdx.x;
    const float4* xp = reinterpret_cast<const float4*>(x) + (size_t)bc * HW4;
    float s = 0.f;
    for (int i = threadIdx.x; i < HW4; i += 256) {
        float4 v = xp[i];
        s += (v.x + v.y) + (v.z + v.w);
    }
    for (int off = 32; off > 0; off >>= 1)
        s += __shfl_down(s, off, 64);
    __shared__ float red[4];
    if ((threadIdx.x & 63) == 0) red[threadIdx.x >> 6] = s;
    __syncthreads();
    if (threadIdx.x == 0)
        pooled[bc] = ((red[0] + red[1]) + (red[2] + red[3])) * (1.0f / (float)HW);
}

__global__ __launch_bounds__(256) void conv_kernel(const float* __restrict__ x,
                                                   const float* __restrict__ weight,
                                                   const float* __restrict__ bias,
                                                   const float* __restrict__ rw,
                                                   const float* __restrict__ rb,
                                                   const float* __restrict__ pooled,
                                                   float* __restrict__ out) {
    __shared__ float w_s[OUT_CH][IN_CH];
    __shared__ float b_s[OUT_CH];
    __shared__ float lg[OUT_CH];
    __shared__ unsigned char act[OUT_CH];
    __shared__ short alist[NFILT];
    __shared__ short ilist[NINACT];

    const int b     = blockIdx.x / CHUNKS;
    const int chunk = blockIdx.x % CHUNKS;

    for (int i = threadIdx.x; i < OUT_CH * IN_CH; i += 256)
        (&w_s[0][0])[i] = weight[i];

    if (threadIdx.x < OUT_CH) {
        const int o = threadIdx.x;
        b_s[o] = bias[o];
        float acc = rb[o];
        #pragma unroll
        for (int c = 0; c < IN_CH; ++c)
            acc += pooled[b * IN_CH + c] * rw[o * IN_CH + c];
        lg[o] = acc;
    }
    __syncthreads();

    if (threadIdx.x < OUT_CH) {
        const int o = threadIdx.x;
        const float v = lg[o];
        int rank = 0;
        #pragma unroll
        for (int j = 0; j < OUT_CH; ++j) {
            const float lj = lg[j];
            rank += (lj > v) || (lj == v && j < o);
        }
        const bool a = (rank < NFILT);
        act[o] = a;
        if (a) alist[rank] = (short)o;
    }
    __syncthreads();

    if (threadIdx.x < OUT_CH) {
        const int o = threadIdx.x;
        if (!act[o]) {
            int irank = 0;
            for (int j = 0; j < o; ++j) irank += !act[j];
            ilist[irank] = (short)o;
        }
    }
    __syncthreads();

    const int pos = chunk * 256 + threadIdx.x;
    const float4* x4 = reinterpret_cast<const float4*>(x);
    vfloat4*      o4 = reinterpret_cast<vfloat4*>(out);

    // issue all 32 channel loads (stay in flight during the zero burst)
    float4 xv[IN_CH];
    #pragma unroll
    for (int c = 0; c < IN_CH; ++c)
        xv[c] = x4[(size_t)(b * IN_CH + c) * HW4 + pos];

    // 48 independent zero nt-stores — no load dependency
    const vfloat4 z = {0.f, 0.f, 0.f, 0.f};
    #pragma unroll
    for (int k = 0; k < NINACT; ++k) {
        const int o = ilist[k];
        __builtin_nontemporal_store(z, &o4[(size_t)(b * OUT_CH + o) * HW4 + pos]);
    }

    // 16 active channels
    #pragma unroll
    for (int k = 0; k < NFILT; ++k) {
        const int o = alist[k];
        const float bv = b_s[o];
        vfloat4 r = {bv, bv, bv, bv};
        #pragma unroll
        for (int c = 0; c < IN_CH; ++c) {
            const float w = w_s[o][c];
            r.x += w * xv[c].x;
            r.y += w * xv[c].y;
            r.z += w * xv[c].z;
            r.w += w * xv[c].w;
        }
        __builtin_nontemporal_store(r, &o4[(size_t)(b * OUT_CH + o) * HW4 + pos]);
    }
}

// ---------------------------------------------------------------------------
extern "C" void kernel_launch(void* const* d_in, const int* in_sizes, int n_in,
                              void* d_out, int out_size, void* d_ws, size_t ws_size,
                              hipStream_t stream) {
    const float* x    = (const float*)d_in[0];
    const float* w    = (const float*)d_in[1];
    const float* bias = (const float*)d_in[2];
    const float* rw   = (const float*)d_in[3];
    const float* rb   = (const float*)d_in[4];
    float* out    = (float*)d_out;
    float* pooled = (float*)d_ws;  // BATCH*IN_CH floats

    pool_kernel<<<BATCH * IN_CH, 256, 0, stream>>>(x, pooled);
    conv_kernel<<<BATCH * CHUNKS, 256, 0, stream>>>(x, w, bias, rw, rb, pooled, out);
}